// Round 1
// baseline (48.080 us; speedup 1.0000x reference)
//
#include <hip/hip_runtime.h>

#define H_IN 224
#define W_IN 224
#define H_T  240
#define W_T  240
#define S1   17
#define S2   17
#define NS   (S1*S2)          // 289
#define NB   8
#define NPIX (H_IN*W_IN)      // 50176
#define TPIX (H_T*W_T)        // 57600
#define ROWG 4
#define ROWS_PER_BLOCK (H_IN/ROWG)      // 56
#define ROWS_PER_WAVE  (ROWS_PER_BLOCK/4) // 14

// ws float layout:
//   part : [B][S1][ROWG][S2]  -> 8*17*4*17 = 9248 floats @ 0
//   fpart: [B][4]             -> 32 floats  @ 9248
//   loss : [B]                -> 8 floats   @ 9280
//   best : [B] (int)          -> 8 ints     @ 9288
#define WS_PART  0
#define WS_FPART 9248
#define WS_LOSS  9280
#define WS_BEST  9288

// ---------------- kernel 1: cross-correlation partials ----------------
__global__ __launch_bounds__(256) void corr_kernel(const float* __restrict__ logits,
                                                   const float* __restrict__ targ,
                                                   float* __restrict__ part) {
    int bid  = blockIdx.x;              // b*S1*ROWG + i*ROWG + rg
    int rg   = bid % ROWG;
    int i    = (bid / ROWG) % S1;
    int b    = bid / (ROWG * S1);
    int tid  = threadIdx.x;
    int lane = tid & 63;
    int w    = tid >> 6;

    float acc[S2];
#pragma unroll
    for (int j = 0; j < S2; ++j) acc[j] = 0.f;

    const float* Lbase = logits + b * NPIX;
    const float* Tbase = targ   + b * TPIX;

    for (int r = 0; r < ROWS_PER_WAVE; ++r) {
        int y = rg * ROWS_PER_BLOCK + w * ROWS_PER_WAVE + r;
        const float* Lrow = Lbase + y * W_IN;
        const float* Trow = Tbase + (y + i) * W_T;
#pragma unroll
        for (int xb = 0; xb < 4; ++xb) {
            int x = xb * 64 + lane;
            if (x < W_IN) {
                float l = Lrow[x];
#pragma unroll
                for (int j = 0; j < S2; ++j)
                    acc[j] = fmaf(l, Trow[x + j], acc[j]);
            }
        }
    }

    // wave shuffle reduce (64 lanes)
#pragma unroll
    for (int j = 0; j < S2; ++j) {
        float v = acc[j];
#pragma unroll
        for (int off = 32; off > 0; off >>= 1)
            v += __shfl_down(v, off, 64);
        acc[j] = v;
    }

    __shared__ float red[4][S2];
    if (lane == 0) {
#pragma unroll
        for (int j = 0; j < S2; ++j) red[w][j] = acc[j];
    }
    __syncthreads();
    if (tid < S2) {
        float v = red[0][tid] + red[1][tid] + red[2][tid] + red[3][tid];
        part[((b * S1 + i) * ROWG + rg) * S2 + tid] = v;
    }
}

// ---------------- kernel 2: shift-invariant term F_b (partials) ----------------
__global__ __launch_bounds__(256) void fsum_kernel(const float* __restrict__ logits,
                                                   float* __restrict__ fpart) {
    int b   = blockIdx.x >> 2;          // 32 blocks: b*4 + q
    int q   = blockIdx.x & 3;
    int tid = threadIdx.x;
    int lane = tid & 63;
    int w    = tid >> 6;

    const float4* L4 = (const float4*)(logits + b * NPIX);
    const int Q = (NPIX / 4) / 4;       // 3136 float4 per quarter
    float s = 0.f;
    for (int k = tid; k < Q; k += 256) {
        float4 v = L4[q * Q + k];
        float vs[4] = {v.x, v.y, v.z, v.w};
#pragma unroll
        for (int u = 0; u < 4; ++u) {
            float l = vs[u];
            s += fmaxf(l, 0.f) + log1pf(expf(-fabsf(l)));
        }
    }
#pragma unroll
    for (int off = 32; off > 0; off >>= 1)
        s += __shfl_down(s, off, 64);

    __shared__ float red[4];
    if (lane == 0) red[w] = s;
    __syncthreads();
    if (tid == 0)
        fpart[b * 4 + q] = red[0] + red[1] + red[2] + red[3];
}

// ---------------- kernel 3: argmax per sample + loss_b ----------------
__global__ __launch_bounds__(64) void argmax_kernel(const float* __restrict__ ws) {
    int b    = blockIdx.x;
    int lane = threadIdx.x;
    const float* part = ws + WS_PART;

    float bv  = -3.4e38f;
    int   bidx = NS;                    // larger than any valid index
    for (int s = lane; s < NS; s += 64) {
        int i = s / S2, j = s % S2;
        const float* p = part + ((b * S1 + i) * ROWG) * S2 + j;
        float v = p[0] + p[S2] + p[2 * S2] + p[3 * S2];
        if (v > bv) { bv = v; bidx = s; }   // ascending s -> earliest tie kept
    }
#pragma unroll
    for (int off = 32; off > 0; off >>= 1) {
        float ov = __shfl_down(bv, off, 64);
        int   oi = __shfl_down(bidx, off, 64);
        if (ov > bv || (ov == bv && oi < bidx)) { bv = ov; bidx = oi; }
    }
    if (lane == 0) {
        const float* fpart = ws + WS_FPART;
        float F = fpart[b * 4 + 0] + fpart[b * 4 + 1] + fpart[b * 4 + 2] + fpart[b * 4 + 3];
        float* loss = (float*)ws + WS_LOSS;
        int*   best = (int*)ws + WS_BEST;
        loss[b] = (F - bv) * (1.0f / (float)NPIX);
        best[b] = bidx;
    }
}

// ---------------- kernel 4: copy best windows + total loss ----------------
__global__ __launch_bounds__(256) void copy_kernel(const float* __restrict__ targ,
                                                   const float* __restrict__ ws,
                                                   float* __restrict__ out) {
    int e = blockIdx.x * 256 + threadIdx.x;
    const int N = NB * NPIX;            // 401408
    if (e < N) {
        int b = e / NPIX;
        int r = e - b * NPIX;
        int y = r / W_IN;
        int x = r - y * W_IN;
        const int* best = (const int*)ws + WS_BEST;
        int s = best[b];
        int i = s / S2, j = s % S2;
        out[1 + e] = targ[b * TPIX + (y + i) * W_T + (x + j)];
    }
    if (e == 0) {
        const float* loss = ws + WS_LOSS;
        float tl = 0.f;
#pragma unroll
        for (int k = 0; k < NB; ++k) tl += loss[k];
        out[0] = tl;
    }
}

extern "C" void kernel_launch(void* const* d_in, const int* in_sizes, int n_in,
                              void* d_out, int out_size, void* d_ws, size_t ws_size,
                              hipStream_t stream) {
    const float* logits = (const float*)d_in[0];   // [8,1,224,224]
    const float* targ   = (const float*)d_in[1];   // [8,1,240,240]
    float* out = (float*)d_out;                    // [1 + 8*224*224]
    float* ws  = (float*)d_ws;

    corr_kernel<<<NB * S1 * ROWG, 256, 0, stream>>>(logits, targ, ws + WS_PART);
    fsum_kernel<<<NB * 4, 256, 0, stream>>>(logits, ws + WS_FPART);
    argmax_kernel<<<NB, 64, 0, stream>>>(ws);
    copy_kernel<<<(NB * NPIX + 255) / 256, 256, 0, stream>>>(targ, ws, out);
}

// Round 3
// 33.139 us; speedup vs baseline: 1.4509x; 1.4509x over previous
//
#include <hip/hip_runtime.h>
#include <float.h>

#define H_IN 224
#define W_IN 224
#define H_T  240
#define W_T  240
#define S1   17
#define S2   17
#define NS   (S1*S2)          // 289
#define NB   8
#define NPIX (H_IN*W_IN)      // 50176
#define TPIX (H_T*W_T)        // 57600
#define ROWG 4
#define ROWS_PER_BLOCK (H_IN/ROWG)        // 56
#define ROWS_PER_WAVE  (ROWS_PER_BLOCK/4) // 14
#define PB   (NPIX/256)       // 196 copy-blocks per sample (exact)

// ws float layout:
//   part : [B][S1][ROWG][S2]  -> 8*17*4*17 = 9248 floats @ 0
//   fpart: [B][ROWG]          -> 32 floats @ 9248
#define WS_PART  0
#define WS_FPART 9248

// ---------------- kernel 1: corr partials + fused f(l) partials ----------------
// block = (b, i, rg). 256 threads = 4 waves; each wave does 14 rows; lanes 0..55
// each own 4 consecutive x (float4). 6 vector loads per row feed 68 FMAs.
__global__ __launch_bounds__(256) void corr_f_kernel(const float* __restrict__ logits,
                                                     const float* __restrict__ targ,
                                                     float* __restrict__ ws) {
    int bid  = blockIdx.x;              // b*S1*ROWG + i*ROWG + rg
    int rg   = bid % ROWG;
    int i    = (bid / ROWG) % S1;
    int b    = bid / (ROWG * S1);
    int tid  = threadIdx.x;
    int lane = tid & 63;
    int w    = tid >> 6;
    bool active = lane < (W_IN / 4);    // 56 active lanes

    float acc[S2];
#pragma unroll
    for (int j = 0; j < S2; ++j) acc[j] = 0.f;
    float fs = 0.f;

    const float* Lb = logits + b * NPIX;
    const float* Tb = targ   + b * TPIX;
    const int y0 = rg * ROWS_PER_BLOCK + w * ROWS_PER_WAVE;
    const bool do_f = (i == 0);

    for (int r = 0; r < ROWS_PER_WAVE; ++r) {
        int y = y0 + r;
        if (active) {
            const float4 l4 = *(const float4*)(Lb + y * W_IN + lane * 4);
            const float* Tr = Tb + (y + i) * W_T + lane * 4;
            float4 t0 = *(const float4*)(Tr);
            float4 t1 = *(const float4*)(Tr + 4);
            float4 t2 = *(const float4*)(Tr + 8);
            float4 t3 = *(const float4*)(Tr + 12);
            float4 t4 = *(const float4*)(Tr + 16);
            float t[20] = {t0.x,t0.y,t0.z,t0.w, t1.x,t1.y,t1.z,t1.w,
                           t2.x,t2.y,t2.z,t2.w, t3.x,t3.y,t3.z,t3.w,
                           t4.x,t4.y,t4.z,t4.w};
            float l[4] = {l4.x, l4.y, l4.z, l4.w};
#pragma unroll
            for (int j = 0; j < S2; ++j) {
                float s = acc[j];
                s = fmaf(l[0], t[j],     s);
                s = fmaf(l[1], t[j + 1], s);
                s = fmaf(l[2], t[j + 2], s);
                s = fmaf(l[3], t[j + 3], s);
                acc[j] = s;
            }
            if (do_f) {
#pragma unroll
                for (int u = 0; u < 4; ++u) {
                    float v = l[u];
                    fs += fmaxf(v, 0.f) + __logf(1.f + __expf(-fabsf(v)));
                }
            }
        }
    }

    // wave butterfly reduce (inactive lanes hold 0)
#pragma unroll
    for (int j = 0; j < S2; ++j) {
        float v = acc[j];
#pragma unroll
        for (int off = 32; off > 0; off >>= 1)
            v += __shfl_xor(v, off, 64);
        acc[j] = v;
    }

    __shared__ float red[4][S2];
    __shared__ float redf[4];
    if (lane == 0) {
#pragma unroll
        for (int j = 0; j < S2; ++j) red[w][j] = acc[j];
    }
    if (do_f) {
#pragma unroll
        for (int off = 32; off > 0; off >>= 1)
            fs += __shfl_xor(fs, off, 64);
        if (lane == 0) redf[w] = fs;
    }
    __syncthreads();
    if (tid < S2) {
        float v = red[0][tid] + red[1][tid] + red[2][tid] + red[3][tid];
        ws[WS_PART + ((b * S1 + i) * ROWG + rg) * S2 + tid] = v;
    }
    if (do_f && tid == 0)
        ws[WS_FPART + b * ROWG + rg] = redf[0] + redf[1] + redf[2] + redf[3];
}

// ---------------- kernel 2: argmax (redundant per block) + copy + loss ----------------
__device__ __forceinline__ void argmax_for(const float* __restrict__ part, int bb,
                                           int tid, int lane, int w,
                                           float* s_v, int* s_i,
                                           float& o_v, int& o_i) {
    __syncthreads();                    // protect shared reuse across calls
    float bv = -FLT_MAX;
    int   bs = NS;
    for (int s = tid; s < NS; s += 256) {
        const float* pp = part + ((bb * S1 + s / S2) * ROWG) * S2 + (s % S2);
        float v = pp[0] + pp[S2] + pp[2 * S2] + pp[3 * S2];
        if (v > bv) { bv = v; bs = s; } // s ascending -> earliest tie kept
    }
#pragma unroll
    for (int off = 32; off > 0; off >>= 1) {
        float ov = __shfl_down(bv, off, 64);
        int   oi = __shfl_down(bs, off, 64);
        if (ov > bv || (ov == bv && oi < bs)) { bv = ov; bs = oi; }
    }
    if (lane == 0) { s_v[w] = bv; s_i[w] = bs; }
    __syncthreads();
    if (tid == 0) {
        float fv = s_v[0]; int fi = s_i[0];
#pragma unroll
        for (int k = 1; k < 4; ++k) {
            if (s_v[k] > fv || (s_v[k] == fv && s_i[k] < fi)) { fv = s_v[k]; fi = s_i[k]; }
        }
        s_v[4] = fv; s_i[4] = fi;
    }
    __syncthreads();
    o_v = s_v[4];
    o_i = s_i[4];
}

__global__ __launch_bounds__(256) void finish_kernel(const float* __restrict__ targ,
                                                     const float* __restrict__ ws,
                                                     float* __restrict__ out) {
    int blk = blockIdx.x;               // b*PB + p
    int p   = blk % PB;
    int b   = blk / PB;
    int tid = threadIdx.x;
    int lane = tid & 63;
    int w    = tid >> 6;

    const float* part  = ws + WS_PART;
    const float* fpart = ws + WS_FPART;

    __shared__ float s_v[5];
    __shared__ int   s_i[5];

    float bv; int best;
    if (blk == 0) {
        float total = 0.f;
#pragma unroll 1
        for (int bb = 0; bb < NB; ++bb) {
            float v; int s;
            argmax_for(part, bb, tid, lane, w, s_v, s_i, v, s);
            if (bb == b) { bv = v; best = s; }
            if (tid == 0) {
                float F = fpart[bb * ROWG] + fpart[bb * ROWG + 1] +
                          fpart[bb * ROWG + 2] + fpart[bb * ROWG + 3];
                total += (F - v) * (1.0f / (float)NPIX);
            }
        }
        if (tid == 0) out[0] = total;
    } else {
        argmax_for(part, b, tid, lane, w, s_v, s_i, bv, best);
    }

    int pix = p * 256 + tid;            // < 50176 exactly
    int y = pix / W_IN;
    int x = pix - y * W_IN;
    int i = best / S2;
    int j = best - i * S2;
    out[1 + b * NPIX + pix] = targ[b * TPIX + (y + i) * W_T + (x + j)];
}

extern "C" void kernel_launch(void* const* d_in, const int* in_sizes, int n_in,
                              void* d_out, int out_size, void* d_ws, size_t ws_size,
                              hipStream_t stream) {
    const float* logits = (const float*)d_in[0];   // [8,1,224,224]
    const float* targ   = (const float*)d_in[1];   // [8,1,240,240]
    float* out = (float*)d_out;                    // [1 + 8*224*224]
    float* ws  = (float*)d_ws;

    corr_f_kernel<<<NB * S1 * ROWG, 256, 0, stream>>>(logits, targ, ws);
    finish_kernel<<<NB * PB, 256, 0, stream>>>(targ, ws, out);
}

// Round 4
// 25.912 us; speedup vs baseline: 1.8555x; 1.2789x over previous
//
#include <hip/hip_runtime.h>
#include <float.h>

#define H_IN 224
#define W_IN 224
#define H_T  240
#define W_T  240
#define S1   17
#define S2   17
#define NS   (S1*S2)          // 289
#define NB   8
#define NPIX (H_IN*W_IN)      // 50176
#define TPIX (H_T*W_T)        // 57600
#define ROWG 4
#define ROWS_PER_BLOCK (H_IN/ROWG)        // 56
#define ROWS_PER_WAVE  (ROWS_PER_BLOCK/4) // 14
#define PB   (NPIX/256)       // 196 copy-blocks per sample (exact)

// ws float layout:
//   part : [B][S1][ROWG][S2]  -> 8*17*4*17 = 9248 floats @ 0
//   fpart: [B][ROWG]          -> 32 floats @ 9248
#define WS_PART  0
#define WS_FPART 9248

// ---------------- kernel 1: corr partials + fused f(l) partials ----------------
// block = (b, i, rg). 256 threads = 4 waves; each wave does 14 rows; lanes 0..55
// each own 4 consecutive x (float4). 6 vector loads per row feed 68 FMAs.
__global__ __launch_bounds__(256) void corr_f_kernel(const float* __restrict__ logits,
                                                     const float* __restrict__ targ,
                                                     float* __restrict__ ws) {
    int bid  = blockIdx.x;              // b*S1*ROWG + i*ROWG + rg
    int rg   = bid % ROWG;
    int i    = (bid / ROWG) % S1;
    int b    = bid / (ROWG * S1);
    int tid  = threadIdx.x;
    int lane = tid & 63;
    int w    = tid >> 6;
    bool active = lane < (W_IN / 4);    // 56 active lanes

    float acc[S2];
#pragma unroll
    for (int j = 0; j < S2; ++j) acc[j] = 0.f;
    float fs = 0.f;

    const float* Lb = logits + b * NPIX;
    const float* Tb = targ   + b * TPIX;
    const int y0 = rg * ROWS_PER_BLOCK + w * ROWS_PER_WAVE;
    const bool do_f = (i == 0);

    for (int r = 0; r < ROWS_PER_WAVE; ++r) {
        int y = y0 + r;
        if (active) {
            const float4 l4 = *(const float4*)(Lb + y * W_IN + lane * 4);
            const float* Tr = Tb + (y + i) * W_T + lane * 4;
            float4 t0 = *(const float4*)(Tr);
            float4 t1 = *(const float4*)(Tr + 4);
            float4 t2 = *(const float4*)(Tr + 8);
            float4 t3 = *(const float4*)(Tr + 12);
            float4 t4 = *(const float4*)(Tr + 16);
            float t[20] = {t0.x,t0.y,t0.z,t0.w, t1.x,t1.y,t1.z,t1.w,
                           t2.x,t2.y,t2.z,t2.w, t3.x,t3.y,t3.z,t3.w,
                           t4.x,t4.y,t4.z,t4.w};
            float l[4] = {l4.x, l4.y, l4.z, l4.w};
#pragma unroll
            for (int j = 0; j < S2; ++j) {
                float s = acc[j];
                s = fmaf(l[0], t[j],     s);
                s = fmaf(l[1], t[j + 1], s);
                s = fmaf(l[2], t[j + 2], s);
                s = fmaf(l[3], t[j + 3], s);
                acc[j] = s;
            }
            if (do_f) {
#pragma unroll
                for (int u = 0; u < 4; ++u) {
                    float v = l[u];
                    fs += fmaxf(v, 0.f) + __logf(1.f + __expf(-fabsf(v)));
                }
            }
        }
    }

    // wave butterfly reduce (inactive lanes hold 0)
#pragma unroll
    for (int j = 0; j < S2; ++j) {
        float v = acc[j];
#pragma unroll
        for (int off = 32; off > 0; off >>= 1)
            v += __shfl_xor(v, off, 64);
        acc[j] = v;
    }

    __shared__ float red[4][S2];
    __shared__ float redf[4];
    if (lane == 0) {
#pragma unroll
        for (int j = 0; j < S2; ++j) red[w][j] = acc[j];
    }
    if (do_f) {
#pragma unroll
        for (int off = 32; off > 0; off >>= 1)
            fs += __shfl_xor(fs, off, 64);
        if (lane == 0) redf[w] = fs;
    }
    __syncthreads();
    if (tid < S2) {
        float v = red[0][tid] + red[1][tid] + red[2][tid] + red[3][tid];
        ws[WS_PART + ((b * S1 + i) * ROWG + rg) * S2 + tid] = v;
    }
    if (do_f && tid == 0)
        ws[WS_FPART + b * ROWG + rg] = redf[0] + redf[1] + redf[2] + redf[3];
}

// ---------------- kernel 2: argmax (per-sample, wave-parallel for block 0) + copy + loss ----------------
__device__ __forceinline__ void argmax_for(const float* __restrict__ part, int bb,
                                           int tid, int lane, int w,
                                           float* s_v, int* s_i,
                                           float& o_v, int& o_i) {
    float bv = -FLT_MAX;
    int   bs = NS;
    for (int s = tid; s < NS; s += 256) {
        const float* pp = part + ((bb * S1 + s / S2) * ROWG) * S2 + (s % S2);
        float v = pp[0] + pp[S2] + pp[2 * S2] + pp[3 * S2];
        if (v > bv) { bv = v; bs = s; } // s ascending -> earliest tie kept
    }
#pragma unroll
    for (int off = 32; off > 0; off >>= 1) {
        float ov = __shfl_down(bv, off, 64);
        int   oi = __shfl_down(bs, off, 64);
        if (ov > bv || (ov == bv && oi < bs)) { bv = ov; bs = oi; }
    }
    if (lane == 0) { s_v[w] = bv; s_i[w] = bs; }
    __syncthreads();
    if (tid == 0) {
        float fv = s_v[0]; int fi = s_i[0];
#pragma unroll
        for (int k = 1; k < 4; ++k) {
            if (s_v[k] > fv || (s_v[k] == fv && s_i[k] < fi)) { fv = s_v[k]; fi = s_i[k]; }
        }
        s_v[4] = fv; s_i[4] = fi;
    }
    __syncthreads();
    o_v = s_v[4];
    o_i = s_i[4];
}

__global__ __launch_bounds__(256) void finish_kernel(const float* __restrict__ targ,
                                                     const float* __restrict__ ws,
                                                     float* __restrict__ out) {
    int blk = blockIdx.x;               // b*PB + p
    int p   = blk % PB;
    int b   = blk / PB;
    int tid = threadIdx.x;
    int lane = tid & 63;
    int w    = tid >> 6;

    const float* part  = ws + WS_PART;
    const float* fpart = ws + WS_FPART;

    __shared__ float s_v[5];
    __shared__ int   s_i[5];
    __shared__ float s_v8[NB];
    __shared__ int   s_i8[NB];

    float bv; int best;
    if (blk == 0) {
        // wave-parallel: 4 waves x 2 passes cover all 8 samples, one barrier total
#pragma unroll
        for (int pass = 0; pass < 2; ++pass) {
            int bb = w + pass * 4;
            float bv2 = -FLT_MAX;
            int   bs2 = NS;
            for (int s = lane; s < NS; s += 64) {
                const float* pp = part + ((bb * S1 + s / S2) * ROWG) * S2 + (s % S2);
                float v = pp[0] + pp[S2] + pp[2 * S2] + pp[3 * S2];
                if (v > bv2) { bv2 = v; bs2 = s; }
            }
#pragma unroll
            for (int off = 32; off > 0; off >>= 1) {
                float ov = __shfl_down(bv2, off, 64);
                int   oi = __shfl_down(bs2, off, 64);
                if (ov > bv2 || (ov == bv2 && oi < bs2)) { bv2 = ov; bs2 = oi; }
            }
            if (lane == 0) { s_v8[bb] = bv2; s_i8[bb] = bs2; }
        }
        __syncthreads();
        if (tid == 0) {
            float total = 0.f;
#pragma unroll
            for (int bb = 0; bb < NB; ++bb) {
                float F = fpart[bb * ROWG] + fpart[bb * ROWG + 1] +
                          fpart[bb * ROWG + 2] + fpart[bb * ROWG + 3];
                total += (F - s_v8[bb]) * (1.0f / (float)NPIX);
            }
            out[0] = total;
        }
        best = s_i8[0];                 // blk 0 has b == 0
    } else {
        argmax_for(part, b, tid, lane, w, s_v, s_i, bv, best);
    }

    int pix = p * 256 + tid;            // < 50176 exactly
    int y = pix / W_IN;
    int x = pix - y * W_IN;
    int i = best / S2;
    int j = best - i * S2;
    out[1 + b * NPIX + pix] = targ[b * TPIX + (y + i) * W_T + (x + j)];
}

extern "C" void kernel_launch(void* const* d_in, const int* in_sizes, int n_in,
                              void* d_out, int out_size, void* d_ws, size_t ws_size,
                              hipStream_t stream) {
    const float* logits = (const float*)d_in[0];   // [8,1,224,224]
    const float* targ   = (const float*)d_in[1];   // [8,1,240,240]
    float* out = (float*)d_out;                    // [1 + 8*224*224]
    float* ws  = (float*)d_ws;

    corr_f_kernel<<<NB * S1 * ROWG, 256, 0, stream>>>(logits, targ, ws);
    finish_kernel<<<NB * PB, 256, 0, stream>>>(targ, ws, out);
}